// Round 10
// baseline (217.086 us; speedup 1.0000x reference)
//
#include <hip/hip_runtime.h>

#define N_NODES 100000
#define N_EDGES 1600000
#define FT 128

// ---- workspace layout (bytes) ----------------------------------------------
// h_bf       [0,            25,600,000)   N_NODES*FT*2 (bf16)
// row_start  [25,600,000,   26,000,016)   (N_NODES+1) ints, padded
// counts     [26,000,016,   38,800,016)   8 replicas x N_NODES, CSTRIDE_R=4 ints
// sorted     [38,800,016,   51,600,016)   N_EDGES int2 (col, val_bits)
// rank16     [51,600,016,   54,800,016)   N_EDGES ushort: (rep<<13)|local_rank
// bsums      [54,800,016,   54,802,064)   512 ints
#define OFF_H 0
#define OFF_ROWSTART 25600000
#define OFF_COUNTS 26000016
#define OFF_SORTED 38800016
#define OFF_RANK 51600016
#define OFF_BSUMS 54800016
#define WS_NEEDED 54802064

#define NREP 8       // one counter replica per XCD (blockIdx & 7 ~ XCD id)
#define CSTRIDE_R 4  // ints between counters within a replica (16B)

#define SCAN_CHUNK 1024
#define SCAN_BLOCKS ((N_NODES + SCAN_CHUNK - 1) / SCAN_CHUNK)  // 98

typedef __attribute__((ext_vector_type(8))) short bf16x8;
typedef __attribute__((ext_vector_type(4))) float f32x4;

// bf16 helpers (RNE pack, shift-unpack).
static __device__ __forceinline__ ushort f2bf(float f) {
  const unsigned u = __float_as_uint(f);
  return (ushort)((u + 0x7FFF + ((u >> 16) & 1)) >> 16);
}
static __device__ __forceinline__ float bf2f(ushort s) {
  return __uint_as_float((unsigned)s << 16);
}

static __device__ __forceinline__ size_t cidx(int rep, int row) {
  return ((size_t)rep * N_NODES + row) * CSTRIDE_R;
}

// ---------------------------------------------------------------------------
// Kernel 1: dense projection  h = x @ W + b  (bf16 output) via MFMA.
// Block = 256 threads (4 waves); wave = 64 rows x 128 cols.
// W staged in LDS pre-swizzled to 16x16x32 B-fragment order (hi + lo bf16).
// ---------------------------------------------------------------------------
__global__ __launch_bounds__(256) void gemm_bias_kernel(
    const float* __restrict__ x,
    const float* __restrict__ W,
    const float* __restrict__ b,
    ushort* __restrict__ h) {
  __shared__ __align__(16) ushort whi[16384];
  __shared__ __align__(16) ushort wlo[16384];

  const int tid = threadIdx.x;

  for (int idx = tid; idx < 16384; idx += 256) {
    const int k = idx >> 7;
    const int col = idx & 127;
    const float wv = W[idx];
    const ushort hi = f2bf(wv);
    const ushort lo = f2bf(wv - bf2f(hi));
    const int lane_ = (((k >> 3) & 3) << 4) | (col & 15);
    const int pos = ((((k >> 5) << 3) + (col >> 4)) * 64 + lane_) * 8 + (k & 7);
    whi[pos] = hi;
    wlo[pos] = lo;
  }
  __syncthreads();

  const int w = tid >> 6;
  const int lane = tid & 63;
  const int r0 = blockIdx.x * 256 + w * 64;
  const int arow = lane & 15;
  const int kgrp = (lane >> 4) << 3;

  float bias_v[8];
#pragma unroll
  for (int ct = 0; ct < 8; ++ct) bias_v[ct] = b[ct * 16 + (lane & 15)];

  f32x4 acc[4][8];
#pragma unroll
  for (int rf = 0; rf < 4; ++rf)
#pragma unroll
    for (int ct = 0; ct < 8; ++ct) acc[rf][ct] = (f32x4){0.f, 0.f, 0.f, 0.f};

#pragma unroll
  for (int ks = 0; ks < 4; ++ks) {
    bf16x8 afr[4];
#pragma unroll
    for (int rf = 0; rf < 4; ++rf) {
      int r = r0 + rf * 16 + arow;
      r = (r < N_NODES) ? r : (N_NODES - 1);
      const float* xp = x + (size_t)r * FT + ks * 32 + kgrp;
      const float4 u0 = *(const float4*)xp;
      const float4 u1 = *(const float4*)(xp + 4);
      bf16x8 a;
      a[0] = (short)f2bf(u0.x);
      a[1] = (short)f2bf(u0.y);
      a[2] = (short)f2bf(u0.z);
      a[3] = (short)f2bf(u0.w);
      a[4] = (short)f2bf(u1.x);
      a[5] = (short)f2bf(u1.y);
      a[6] = (short)f2bf(u1.z);
      a[7] = (short)f2bf(u1.w);
      afr[rf] = a;
    }
#pragma unroll
    for (int ct = 0; ct < 8; ++ct) {
      const int fo = ((ks * 8 + ct) * 64 + lane) * 8;
      const bf16x8 bh = *(const bf16x8*)&whi[fo];
      const bf16x8 bl = *(const bf16x8*)&wlo[fo];
#pragma unroll
      for (int rf = 0; rf < 4; ++rf) {
        acc[rf][ct] = __builtin_amdgcn_mfma_f32_16x16x32_bf16(
            afr[rf], bh, acc[rf][ct], 0, 0, 0);
        acc[rf][ct] = __builtin_amdgcn_mfma_f32_16x16x32_bf16(
            afr[rf], bl, acc[rf][ct], 0, 0, 0);
      }
    }
  }

  const int crow0 = (lane >> 4) << 2;
  const int ccol = lane & 15;
#pragma unroll
  for (int rf = 0; rf < 4; ++rf) {
#pragma unroll
    for (int ct = 0; ct < 8; ++ct) {
      const int col = ct * 16 + ccol;
#pragma unroll
      for (int i = 0; i < 4; ++i) {
        const int row = r0 + rf * 16 + crow0 + i;
        if (row < N_NODES)
          h[(size_t)row * FT + col] = f2bf(acc[rf][ct][i] + bias_v[ct]);
      }
    }
  }
}

// ---------------------------------------------------------------------------
// Kernel 2: fused histogram + rank with per-XCD counter replicas.
// replica = blockIdx & 7 (default round-robin block->XCD mapping) keeps each
// replica's RMW lines resident in ONE XCD's L2 (no cross-XCD line bounce).
// rank word = (replica<<13) | local_rank.
// ---------------------------------------------------------------------------
__global__ __launch_bounds__(256) void hist_rank_kernel(
    const int* __restrict__ erows,
    int* counts,
    ushort* __restrict__ rank) {
  const int i = blockIdx.x * blockDim.x + threadIdx.x;  // int4 group
  if (i * 4 >= N_EDGES) return;  // N_EDGES % 4 == 0
  const int rep = blockIdx.x & (NREP - 1);
  const ushort rbits = (ushort)(rep << 13);
  const int4 r = ((const int4*)erows)[i];
  ushort4 rk;
  rk.x = (ushort)(rbits | (ushort)atomicAdd(&counts[cidx(rep, r.x)], 1));
  rk.y = (ushort)(rbits | (ushort)atomicAdd(&counts[cidx(rep, r.y)], 1));
  rk.z = (ushort)(rbits | (ushort)atomicAdd(&counts[cidx(rep, r.z)], 1));
  rk.w = (ushort)(rbits | (ushort)atomicAdd(&counts[cidx(rep, r.w)], 1));
  ((ushort4*)rank)[i] = rk;
}

// ---------------------------------------------------------------------------
// Scan phase 1: per-block sums of 1024 row-totals (across 8 replicas).
// ---------------------------------------------------------------------------
__global__ __launch_bounds__(256) void scan1_kernel(
    const int* __restrict__ counts, int* __restrict__ bsums) {
  __shared__ int red[256];
  const int t = threadIdx.x;
  const int base = blockIdx.x * SCAN_CHUNK + t * 4;

  int s = 0;
#pragma unroll
  for (int j = 0; j < 4; ++j) {
    const int row = base + j;
    if (row < N_NODES) {
#pragma unroll
      for (int k = 0; k < NREP; ++k) s += counts[cidx(k, row)];
    }
  }
  red[t] = s;
  __syncthreads();
#pragma unroll
  for (int off = 128; off > 0; off >>= 1) {
    if (t < off) red[t] += red[t + off];
    __syncthreads();
  }
  if (t == 0) bsums[blockIdx.x] = red[0];
}

// ---------------------------------------------------------------------------
// Scan phase 2: one tiny block exclusive-scans the 98 block sums in place.
// ---------------------------------------------------------------------------
__global__ __launch_bounds__(128) void scan2_kernel(int* __restrict__ bsums) {
  __shared__ int ps[128];
  const int t = threadIdx.x;
  int v = (t < SCAN_BLOCKS) ? bsums[t] : 0;
  ps[t] = v;
  __syncthreads();
#pragma unroll
  for (int off = 1; off < 128; off <<= 1) {
    const int u = (t >= off) ? ps[t - off] : 0;
    __syncthreads();
    ps[t] += u;
    __syncthreads();
  }
  if (t < SCAN_BLOCKS) bsums[t] = (t == 0) ? 0 : ps[t - 1];
}

// ---------------------------------------------------------------------------
// Scan phase 3: row_start (global exclusive scan of row totals) AND
// in-place transform of counts[k][row] -> per-row per-replica exclusive base.
// ---------------------------------------------------------------------------
__global__ __launch_bounds__(256) void scan3_kernel(
    int* __restrict__ counts,
    const int* __restrict__ bsums,
    int* __restrict__ row_start) {
  __shared__ int ts[256];
  const int t = threadIdx.x;
  const int base = blockIdx.x * SCAN_CHUNK + t * 4;

  int c[4][NREP];
  int tot[4];
  int s = 0;
#pragma unroll
  for (int j = 0; j < 4; ++j) {
    const int row = base + j;
    int rs = 0;
    if (row < N_NODES) {
#pragma unroll
      for (int k = 0; k < NREP; ++k) {
        c[j][k] = counts[cidx(k, row)];
        rs += c[j][k];
      }
    } else {
#pragma unroll
      for (int k = 0; k < NREP; ++k) c[j][k] = 0;
    }
    tot[j] = rs;
    s += rs;
  }
  ts[t] = s;
  __syncthreads();
#pragma unroll
  for (int off = 1; off < 256; off <<= 1) {
    const int u = (t >= off) ? ts[t - off] : 0;
    __syncthreads();
    ts[t] += u;
    __syncthreads();
  }

  if (base < N_NODES) {  // N_NODES % 4 == 0 -> all 4 rows in range
    int run = bsums[blockIdx.x] + ((t == 0) ? 0 : ts[t - 1]);
    int4 rs;
    int* rsp = &rs.x;
#pragma unroll
    for (int j = 0; j < 4; ++j) {
      rsp[j] = run;
      // per-replica exclusive bases for this row, written back in place
      int rb = 0;
#pragma unroll
      for (int k = 0; k < NREP; ++k) {
        const int cv = c[j][k];
        counts[cidx(k, base + j)] = rb;
        rb += cv;
      }
      run += tot[j];
    }
    ((int4*)row_start)[base >> 2] = rs;
  }
  if (blockIdx.x == 0 && t == 0) row_start[N_NODES] = N_EDGES;
}

// ---------------------------------------------------------------------------
// Kernel 4: atomic-free scatter.
// pos = row_start[row] + rep_base[rep][row] + local_rank.
// ---------------------------------------------------------------------------
__global__ __launch_bounds__(256) void scatter_rank_kernel(
    const int* __restrict__ erows,
    const int* __restrict__ ecols,
    const float* __restrict__ evals,
    const ushort* __restrict__ rank,
    const int* __restrict__ row_start,
    const int* __restrict__ rep_base,
    int2* __restrict__ sorted) {
  const int i = blockIdx.x * blockDim.x + threadIdx.x;  // int4 group
  if (i * 4 >= N_EDGES) return;
  const int4 r = ((const int4*)erows)[i];
  const int4 c = ((const int4*)ecols)[i];
  const float4 v = ((const float4*)evals)[i];
  const ushort4 rk = ((const ushort4*)rank)[i];

  const int p0 = row_start[r.x] + rep_base[cidx(rk.x >> 13, r.x)] + (rk.x & 0x1FFF);
  const int p1 = row_start[r.y] + rep_base[cidx(rk.y >> 13, r.y)] + (rk.y & 0x1FFF);
  const int p2 = row_start[r.z] + rep_base[cidx(rk.z >> 13, r.z)] + (rk.z & 0x1FFF);
  const int p3 = row_start[r.w] + rep_base[cidx(rk.w >> 13, r.w)] + (rk.w & 0x1FFF);

  int2 s0; s0.x = c.x; s0.y = __float_as_int(v.x);
  int2 s1; s1.x = c.y; s1.y = __float_as_int(v.y);
  int2 s2; s2.x = c.z; s2.y = __float_as_int(v.z);
  int2 s3; s3.x = c.w; s3.y = __float_as_int(v.w);
  sorted[p0] = s0;
  sorted[p1] = s1;
  sorted[p2] = s2;
  sorted[p3] = s3;
}

// ---------------------------------------------------------------------------
// Kernel 5: CSR SpMM + fused ReLU. One 32-lane group per output row;
// bf16 h gather (8B/lane/edge), 4-edge unroll for load ILP.
// ---------------------------------------------------------------------------
__global__ __launch_bounds__(256) void spmm_csr_kernel(
    const int* __restrict__ row_start,
    const int2* __restrict__ sorted,
    const ushort* __restrict__ h,
    float* __restrict__ out) {
  const int tid = threadIdx.x;
  const int row = blockIdx.x * 8 + (tid >> 5);
  if (row >= N_NODES) return;

  const int beg = row_start[row];
  const int end = row_start[row + 1];
  const int j = (tid & 31) * 4;

  float a0 = 0.f, a1 = 0.f, a2 = 0.f, a3 = 0.f;

  int e = beg;
  for (; e + 3 < end; e += 4) {
    const int2 p0 = sorted[e];
    const int2 p1 = sorted[e + 1];
    const int2 p2 = sorted[e + 2];
    const int2 p3 = sorted[e + 3];
    const ushort4 q0 = *(const ushort4*)(h + (size_t)p0.x * FT + j);
    const ushort4 q1 = *(const ushort4*)(h + (size_t)p1.x * FT + j);
    const ushort4 q2 = *(const ushort4*)(h + (size_t)p2.x * FT + j);
    const ushort4 q3 = *(const ushort4*)(h + (size_t)p3.x * FT + j);
    const float v0 = __int_as_float(p0.y);
    const float v1 = __int_as_float(p1.y);
    const float v2 = __int_as_float(p2.y);
    const float v3 = __int_as_float(p3.y);
    a0 = fmaf(v0, bf2f(q0.x), a0);
    a1 = fmaf(v0, bf2f(q0.y), a1);
    a2 = fmaf(v0, bf2f(q0.z), a2);
    a3 = fmaf(v0, bf2f(q0.w), a3);
    a0 = fmaf(v1, bf2f(q1.x), a0);
    a1 = fmaf(v1, bf2f(q1.y), a1);
    a2 = fmaf(v1, bf2f(q1.z), a2);
    a3 = fmaf(v1, bf2f(q1.w), a3);
    a0 = fmaf(v2, bf2f(q2.x), a0);
    a1 = fmaf(v2, bf2f(q2.y), a1);
    a2 = fmaf(v2, bf2f(q2.z), a2);
    a3 = fmaf(v2, bf2f(q2.w), a3);
    a0 = fmaf(v3, bf2f(q3.x), a0);
    a1 = fmaf(v3, bf2f(q3.y), a1);
    a2 = fmaf(v3, bf2f(q3.z), a2);
    a3 = fmaf(v3, bf2f(q3.w), a3);
  }
  for (; e < end; ++e) {
    const int2 p0 = sorted[e];
    const float v0 = __int_as_float(p0.y);
    const ushort4 q0 = *(const ushort4*)(h + (size_t)p0.x * FT + j);
    a0 = fmaf(v0, bf2f(q0.x), a0);
    a1 = fmaf(v0, bf2f(q0.y), a1);
    a2 = fmaf(v0, bf2f(q0.z), a2);
    a3 = fmaf(v0, bf2f(q0.w), a3);
  }

  float4 r;
  r.x = fmaxf(a0, 0.f);
  r.y = fmaxf(a1, 0.f);
  r.z = fmaxf(a2, 0.f);
  r.w = fmaxf(a3, 0.f);
  *(float4*)(out + (size_t)row * FT + j) = r;
}

// ---------------------------------------------------------------------------
// Fallback (small ws): atomic scatter + relu on bf16 h.
// ---------------------------------------------------------------------------
__global__ __launch_bounds__(256) void edge_scatter_kernel(
    const int* __restrict__ erows,
    const int* __restrict__ ecols,
    const float* __restrict__ evals,
    const ushort* __restrict__ h,
    float* out) {
  const int tid = threadIdx.x;
  const int e = blockIdx.x * 8 + (tid >> 5);
  if (e >= N_EDGES) return;
  const int r = erows[e];
  const int c = ecols[e];
  const float v = evals[e];
  const int j = (tid & 31) * 4;
  const ushort4 q = *(const ushort4*)(h + (size_t)c * FT + j);
  float* op = out + (size_t)r * FT + j;
  atomicAdd(op + 0, v * bf2f(q.x));
  atomicAdd(op + 1, v * bf2f(q.y));
  atomicAdd(op + 2, v * bf2f(q.z));
  atomicAdd(op + 3, v * bf2f(q.w));
}

__global__ __launch_bounds__(256) void relu_kernel(float* out, int n4) {
  const int i = blockIdx.x * blockDim.x + threadIdx.x;
  if (i < n4) {
    float4 v = ((float4*)out)[i];
    v.x = fmaxf(v.x, 0.f);
    v.y = fmaxf(v.y, 0.f);
    v.z = fmaxf(v.z, 0.f);
    v.w = fmaxf(v.w, 0.f);
    ((float4*)out)[i] = v;
  }
}

extern "C" void kernel_launch(void* const* d_in, const int* in_sizes, int n_in,
                              void* d_out, int out_size, void* d_ws, size_t ws_size,
                              hipStream_t stream) {
  const float* x = (const float*)d_in[0];
  const int* erows = (const int*)d_in[1];
  const int* ecols = (const int*)d_in[2];
  const float* evals = (const float*)d_in[3];
  const float* W = (const float*)d_in[4];
  const float* b = (const float*)d_in[5];
  float* out = (float*)d_out;

  char* ws = (char*)d_ws;
  ushort* h = (ushort*)(ws + OFF_H);

  gemm_bias_kernel<<<(N_NODES + 255) / 256, 256, 0, stream>>>(x, W, b, h);

  if (ws_size >= (size_t)WS_NEEDED) {
    int* row_start = (int*)(ws + OFF_ROWSTART);
    int* counts = (int*)(ws + OFF_COUNTS);
    int2* sorted = (int2*)(ws + OFF_SORTED);
    ushort* rank = (ushort*)(ws + OFF_RANK);
    int* bsums = (int*)(ws + OFF_BSUMS);

    hipMemsetAsync(counts, 0,
                   (size_t)NREP * N_NODES * CSTRIDE_R * sizeof(int), stream);
    hist_rank_kernel<<<(N_EDGES / 4 + 255) / 256, 256, 0, stream>>>(
        erows, counts, rank);
    scan1_kernel<<<SCAN_BLOCKS, 256, 0, stream>>>(counts, bsums);
    scan2_kernel<<<1, 128, 0, stream>>>(bsums);
    scan3_kernel<<<SCAN_BLOCKS, 256, 0, stream>>>(counts, bsums, row_start);
    scatter_rank_kernel<<<(N_EDGES / 4 + 255) / 256, 256, 0, stream>>>(
        erows, ecols, evals, rank, row_start, counts, sorted);
    spmm_csr_kernel<<<(N_NODES + 7) / 8, 256, 0, stream>>>(row_start, sorted,
                                                           h, out);
  } else {
    hipMemsetAsync(d_out, 0, (size_t)out_size * sizeof(float), stream);
    edge_scatter_kernel<<<(N_EDGES + 7) / 8, 256, 0, stream>>>(erows, ecols,
                                                               evals, h, out);
    const int n4 = out_size / 4;
    relu_kernel<<<(n4 + 255) / 256, 256, 0, stream>>>(out, n4);
  }
}

// Round 11
// 134.362 us; speedup vs baseline: 1.6157x; 1.6157x over previous
//
#include <hip/hip_runtime.h>

#define N_NODES 100000
#define N_EDGES 1600000
#define FT 128

#define NBUCK 391   // row buckets: bucket = row >> 8 (256 rows each)
#define EPB 4096    // edges per partition block
#define NBLKP ((N_EDGES + EPB - 1) / EPB)  // 391 partition blocks

// ---- workspace layout (bytes) ----------------------------------------------
// h_bf        [0,           25,600,000)   N_NODES*FT*2 (bf16)
// row_start   [25,600,000,  26,000,016)   (N_NODES+1) ints, padded
// bucketed    [26,000,016,  38,800,016)   N_EDGES int2 (packed row8|col, val)
// sorted      [38,800,016,  51,600,016)   N_EDGES int2 (col, val_bits)
// blkhist     [51,600,016,  52,211,540)   NBLKP*NBUCK ints (block-major)
// btot        [52,211,544,  52,213,108)   NBUCK ints
// bucket_base [52,213,112,  52,214,684)   NBUCK+1 ints
#define OFF_H 0
#define OFF_ROWSTART 25600000
#define OFF_BUCKETED 26000016
#define OFF_SORTED 38800016
#define OFF_BLKHIST 51600016
#define OFF_BTOT 52211544
#define OFF_BBASE 52213112
#define WS_NEEDED 52214684

typedef __attribute__((ext_vector_type(8))) short bf16x8;
typedef __attribute__((ext_vector_type(4))) float f32x4;

// bf16 helpers (RNE pack, shift-unpack).
static __device__ __forceinline__ ushort f2bf(float f) {
  const unsigned u = __float_as_uint(f);
  return (ushort)((u + 0x7FFF + ((u >> 16) & 1)) >> 16);
}
static __device__ __forceinline__ float bf2f(ushort s) {
  return __uint_as_float((unsigned)s << 16);
}

// ---------------------------------------------------------------------------
// Kernel 1: dense projection  h = x @ W + b  (bf16 output) via MFMA.
// Block = 256 threads (4 waves); wave = 64 rows x 128 cols.
// W staged in LDS pre-swizzled to 16x16x32 B-fragment order (hi + lo bf16).
// ---------------------------------------------------------------------------
__global__ __launch_bounds__(256) void gemm_bias_kernel(
    const float* __restrict__ x,
    const float* __restrict__ W,
    const float* __restrict__ b,
    ushort* __restrict__ h) {
  __shared__ __align__(16) ushort whi[16384];
  __shared__ __align__(16) ushort wlo[16384];

  const int tid = threadIdx.x;

  for (int idx = tid; idx < 16384; idx += 256) {
    const int k = idx >> 7;
    const int col = idx & 127;
    const float wv = W[idx];
    const ushort hi = f2bf(wv);
    const ushort lo = f2bf(wv - bf2f(hi));
    const int lane_ = (((k >> 3) & 3) << 4) | (col & 15);
    const int pos = ((((k >> 5) << 3) + (col >> 4)) * 64 + lane_) * 8 + (k & 7);
    whi[pos] = hi;
    wlo[pos] = lo;
  }
  __syncthreads();

  const int w = tid >> 6;
  const int lane = tid & 63;
  const int r0 = blockIdx.x * 256 + w * 64;
  const int arow = lane & 15;
  const int kgrp = (lane >> 4) << 3;

  float bias_v[8];
#pragma unroll
  for (int ct = 0; ct < 8; ++ct) bias_v[ct] = b[ct * 16 + (lane & 15)];

  f32x4 acc[4][8];
#pragma unroll
  for (int rf = 0; rf < 4; ++rf)
#pragma unroll
    for (int ct = 0; ct < 8; ++ct) acc[rf][ct] = (f32x4){0.f, 0.f, 0.f, 0.f};

#pragma unroll
  for (int ks = 0; ks < 4; ++ks) {
    bf16x8 afr[4];
#pragma unroll
    for (int rf = 0; rf < 4; ++rf) {
      int r = r0 + rf * 16 + arow;
      r = (r < N_NODES) ? r : (N_NODES - 1);
      const float* xp = x + (size_t)r * FT + ks * 32 + kgrp;
      const float4 u0 = *(const float4*)xp;
      const float4 u1 = *(const float4*)(xp + 4);
      bf16x8 a;
      a[0] = (short)f2bf(u0.x);
      a[1] = (short)f2bf(u0.y);
      a[2] = (short)f2bf(u0.z);
      a[3] = (short)f2bf(u0.w);
      a[4] = (short)f2bf(u1.x);
      a[5] = (short)f2bf(u1.y);
      a[6] = (short)f2bf(u1.z);
      a[7] = (short)f2bf(u1.w);
      afr[rf] = a;
    }
#pragma unroll
    for (int ct = 0; ct < 8; ++ct) {
      const int fo = ((ks * 8 + ct) * 64 + lane) * 8;
      const bf16x8 bh = *(const bf16x8*)&whi[fo];
      const bf16x8 bl = *(const bf16x8*)&wlo[fo];
#pragma unroll
      for (int rf = 0; rf < 4; ++rf) {
        acc[rf][ct] = __builtin_amdgcn_mfma_f32_16x16x32_bf16(
            afr[rf], bh, acc[rf][ct], 0, 0, 0);
        acc[rf][ct] = __builtin_amdgcn_mfma_f32_16x16x32_bf16(
            afr[rf], bl, acc[rf][ct], 0, 0, 0);
      }
    }
  }

  const int crow0 = (lane >> 4) << 2;
  const int ccol = lane & 15;
#pragma unroll
  for (int rf = 0; rf < 4; ++rf) {
#pragma unroll
    for (int ct = 0; ct < 8; ++ct) {
      const int col = ct * 16 + ccol;
#pragma unroll
      for (int i = 0; i < 4; ++i) {
        const int row = r0 + rf * 16 + crow0 + i;
        if (row < N_NODES)
          h[(size_t)row * FT + col] = f2bf(acc[rf][ct][i] + bias_v[ct]);
      }
    }
  }
}

// ---------------------------------------------------------------------------
// Pass A: per-block LDS histogram over row buckets -> blkhist[block][bucket].
// ---------------------------------------------------------------------------
__global__ __launch_bounds__(256) void partA_kernel(
    const int* __restrict__ erows, int* __restrict__ blkhist) {
  __shared__ int cnt[NBUCK];
  const int tid = threadIdx.x;
  for (int j = tid; j < NBUCK; j += 256) cnt[j] = 0;
  __syncthreads();

  const int base4 = blockIdx.x * (EPB / 4);
#pragma unroll
  for (int it = 0; it < EPB / 4 / 256; ++it) {
    const int idx4 = base4 + it * 256 + tid;
    if (idx4 < N_EDGES / 4) {
      const int4 r = ((const int4*)erows)[idx4];
      atomicAdd(&cnt[r.x >> 8], 1);
      atomicAdd(&cnt[r.y >> 8], 1);
      atomicAdd(&cnt[r.z >> 8], 1);
      atomicAdd(&cnt[r.w >> 8], 1);
    }
  }
  __syncthreads();
  int* dst = blkhist + (size_t)blockIdx.x * NBUCK;
  for (int j = tid; j < NBUCK; j += 256) dst[j] = cnt[j];
}

// ---------------------------------------------------------------------------
// Pass B1: for each bucket b, exclusive-scan blkhist[k][b] over k (in place);
// btot[b] = total.
// ---------------------------------------------------------------------------
__global__ __launch_bounds__(512) void partB1_kernel(
    int* __restrict__ blkhist, int* __restrict__ btot) {
  __shared__ int ps[512];
  const int b = blockIdx.x;
  const int t = threadIdx.x;
  int v = 0;
  if (t < NBLKP) v = blkhist[(size_t)t * NBUCK + b];
  ps[t] = v;
  __syncthreads();
#pragma unroll
  for (int d = 1; d < 512; d <<= 1) {
    const int u = (t >= d) ? ps[t - d] : 0;
    __syncthreads();
    ps[t] += u;
    __syncthreads();
  }
  if (t < NBLKP) blkhist[(size_t)t * NBUCK + b] = ps[t] - v;  // exclusive
  if (t == NBLKP - 1) btot[b] = ps[t];
}

// ---------------------------------------------------------------------------
// Pass B2: exclusive-scan btot -> bucket_base (+ sentinel = N_EDGES).
// ---------------------------------------------------------------------------
__global__ __launch_bounds__(512) void partB2_kernel(
    const int* __restrict__ btot, int* __restrict__ bucket_base) {
  __shared__ int ps[512];
  const int t = threadIdx.x;
  int v = 0;
  if (t < NBUCK) v = btot[t];
  ps[t] = v;
  __syncthreads();
#pragma unroll
  for (int d = 1; d < 512; d <<= 1) {
    const int u = (t >= d) ? ps[t - d] : 0;
    __syncthreads();
    ps[t] += u;
    __syncthreads();
  }
  if (t < NBUCK) bucket_base[t] = ps[t] - v;
  if (t == NBUCK - 1) bucket_base[NBUCK] = ps[t];
}

// ---------------------------------------------------------------------------
// Pass C: partition scatter. LDS cursors = absolute offsets; each edge goes
// to its bucket region packed as ((row&255)<<24 | col, val_bits).
// Only LDS atomics (fast); one scattered 8B global store per edge.
// ---------------------------------------------------------------------------
__global__ __launch_bounds__(256) void partC_kernel(
    const int* __restrict__ erows,
    const int* __restrict__ ecols,
    const float* __restrict__ evals,
    const int* __restrict__ blkhist,
    const int* __restrict__ bucket_base,
    int2* __restrict__ bucketed) {
  __shared__ int cur[NBUCK];
  const int tid = threadIdx.x;
  const int* src = blkhist + (size_t)blockIdx.x * NBUCK;
  for (int j = tid; j < NBUCK; j += 256) cur[j] = src[j] + bucket_base[j];
  __syncthreads();

  const int base4 = blockIdx.x * (EPB / 4);
#pragma unroll
  for (int it = 0; it < EPB / 4 / 256; ++it) {
    const int idx4 = base4 + it * 256 + tid;
    if (idx4 < N_EDGES / 4) {
      const int4 r = ((const int4*)erows)[idx4];
      const int4 c = ((const int4*)ecols)[idx4];
      const float4 v = ((const float4*)evals)[idx4];
      int p;
      p = atomicAdd(&cur[r.x >> 8], 1);
      bucketed[p] = (int2){((r.x & 255) << 24) | c.x, __float_as_int(v.x)};
      p = atomicAdd(&cur[r.y >> 8], 1);
      bucketed[p] = (int2){((r.y & 255) << 24) | c.y, __float_as_int(v.y)};
      p = atomicAdd(&cur[r.z >> 8], 1);
      bucketed[p] = (int2){((r.z & 255) << 24) | c.z, __float_as_int(v.z)};
      p = atomicAdd(&cur[r.w >> 8], 1);
      bucketed[p] = (int2){((r.w & 255) << 24) | c.w, __float_as_int(v.w)};
    }
  }
}

// ---------------------------------------------------------------------------
// Pass D: per-bucket counting sort (256 rows). Writes final CSR `sorted`
// and row_start. All atomics in LDS.
// ---------------------------------------------------------------------------
__global__ __launch_bounds__(512) void partD_kernel(
    const int2* __restrict__ bucketed,
    const int* __restrict__ bucket_base,
    int* __restrict__ row_start,
    int2* __restrict__ sorted) {
  __shared__ int cnt[256];
  __shared__ int ps[256];
  __shared__ int cur[256];
  const int b = blockIdx.x;
  const int t = threadIdx.x;
  const int beg = bucket_base[b];
  const int end = bucket_base[b + 1];

  if (t < 256) cnt[t] = 0;
  __syncthreads();

  for (int i = beg + t; i < end; i += 512)
    atomicAdd(&cnt[((unsigned)bucketed[i].x) >> 24], 1);
  __syncthreads();

  // inclusive scan of cnt into ps (256 values, threads 0..255 participate)
  if (t < 256) ps[t] = cnt[t];
  __syncthreads();
#pragma unroll
  for (int d = 1; d < 256; d <<= 1) {
    int u = 0;
    if (t < 256 && t >= d) u = ps[t - d];
    __syncthreads();
    if (t < 256) ps[t] += u;
    __syncthreads();
  }

  if (t < 256) {
    const int excl = ps[t] - cnt[t];
    cur[t] = excl;
    const int row = b * 256 + t;
    if (row < N_NODES) row_start[row] = beg + excl;
  }
  if (b == NBUCK - 1 && t == 0) row_start[N_NODES] = N_EDGES;
  __syncthreads();

  for (int i = beg + t; i < end; i += 512) {
    const int2 rec = bucketed[i];
    const int r8 = ((unsigned)rec.x) >> 24;
    const int p = atomicAdd(&cur[r8], 1);
    sorted[beg + p] = (int2){rec.x & 0x00FFFFFF, rec.y};
  }
}

// ---------------------------------------------------------------------------
// Kernel 5: CSR SpMM + fused ReLU. One 32-lane group per output row;
// bf16 h gather (8B/lane/edge), 4-edge unroll for load ILP.
// ---------------------------------------------------------------------------
__global__ __launch_bounds__(256) void spmm_csr_kernel(
    const int* __restrict__ row_start,
    const int2* __restrict__ sorted,
    const ushort* __restrict__ h,
    float* __restrict__ out) {
  const int tid = threadIdx.x;
  const int row = blockIdx.x * 8 + (tid >> 5);
  if (row >= N_NODES) return;

  const int beg = row_start[row];
  const int end = row_start[row + 1];
  const int j = (tid & 31) * 4;

  float a0 = 0.f, a1 = 0.f, a2 = 0.f, a3 = 0.f;

  int e = beg;
  for (; e + 3 < end; e += 4) {
    const int2 p0 = sorted[e];
    const int2 p1 = sorted[e + 1];
    const int2 p2 = sorted[e + 2];
    const int2 p3 = sorted[e + 3];
    const ushort4 q0 = *(const ushort4*)(h + (size_t)p0.x * FT + j);
    const ushort4 q1 = *(const ushort4*)(h + (size_t)p1.x * FT + j);
    const ushort4 q2 = *(const ushort4*)(h + (size_t)p2.x * FT + j);
    const ushort4 q3 = *(const ushort4*)(h + (size_t)p3.x * FT + j);
    const float v0 = __int_as_float(p0.y);
    const float v1 = __int_as_float(p1.y);
    const float v2 = __int_as_float(p2.y);
    const float v3 = __int_as_float(p3.y);
    a0 = fmaf(v0, bf2f(q0.x), a0);
    a1 = fmaf(v0, bf2f(q0.y), a1);
    a2 = fmaf(v0, bf2f(q0.z), a2);
    a3 = fmaf(v0, bf2f(q0.w), a3);
    a0 = fmaf(v1, bf2f(q1.x), a0);
    a1 = fmaf(v1, bf2f(q1.y), a1);
    a2 = fmaf(v1, bf2f(q1.z), a2);
    a3 = fmaf(v1, bf2f(q1.w), a3);
    a0 = fmaf(v2, bf2f(q2.x), a0);
    a1 = fmaf(v2, bf2f(q2.y), a1);
    a2 = fmaf(v2, bf2f(q2.z), a2);
    a3 = fmaf(v2, bf2f(q2.w), a3);
    a0 = fmaf(v3, bf2f(q3.x), a0);
    a1 = fmaf(v3, bf2f(q3.y), a1);
    a2 = fmaf(v3, bf2f(q3.z), a2);
    a3 = fmaf(v3, bf2f(q3.w), a3);
  }
  for (; e < end; ++e) {
    const int2 p0 = sorted[e];
    const float v0 = __int_as_float(p0.y);
    const ushort4 q0 = *(const ushort4*)(h + (size_t)p0.x * FT + j);
    a0 = fmaf(v0, bf2f(q0.x), a0);
    a1 = fmaf(v0, bf2f(q0.y), a1);
    a2 = fmaf(v0, bf2f(q0.z), a2);
    a3 = fmaf(v0, bf2f(q0.w), a3);
  }

  float4 r;
  r.x = fmaxf(a0, 0.f);
  r.y = fmaxf(a1, 0.f);
  r.z = fmaxf(a2, 0.f);
  r.w = fmaxf(a3, 0.f);
  *(float4*)(out + (size_t)row * FT + j) = r;
}

// ---------------------------------------------------------------------------
// Fallback (small ws): atomic scatter + relu on bf16 h.
// ---------------------------------------------------------------------------
__global__ __launch_bounds__(256) void edge_scatter_kernel(
    const int* __restrict__ erows,
    const int* __restrict__ ecols,
    const float* __restrict__ evals,
    const ushort* __restrict__ h,
    float* out) {
  const int tid = threadIdx.x;
  const int e = blockIdx.x * 8 + (tid >> 5);
  if (e >= N_EDGES) return;
  const int r = erows[e];
  const int c = ecols[e];
  const float v = evals[e];
  const int j = (tid & 31) * 4;
  const ushort4 q = *(const ushort4*)(h + (size_t)c * FT + j);
  float* op = out + (size_t)r * FT + j;
  atomicAdd(op + 0, v * bf2f(q.x));
  atomicAdd(op + 1, v * bf2f(q.y));
  atomicAdd(op + 2, v * bf2f(q.z));
  atomicAdd(op + 3, v * bf2f(q.w));
}

__global__ __launch_bounds__(256) void relu_kernel(float* out, int n4) {
  const int i = blockIdx.x * blockDim.x + threadIdx.x;
  if (i < n4) {
    float4 v = ((float4*)out)[i];
    v.x = fmaxf(v.x, 0.f);
    v.y = fmaxf(v.y, 0.f);
    v.z = fmaxf(v.z, 0.f);
    v.w = fmaxf(v.w, 0.f);
    ((float4*)out)[i] = v;
  }
}

extern "C" void kernel_launch(void* const* d_in, const int* in_sizes, int n_in,
                              void* d_out, int out_size, void* d_ws, size_t ws_size,
                              hipStream_t stream) {
  const float* x = (const float*)d_in[0];
  const int* erows = (const int*)d_in[1];
  const int* ecols = (const int*)d_in[2];
  const float* evals = (const float*)d_in[3];
  const float* W = (const float*)d_in[4];
  const float* b = (const float*)d_in[5];
  float* out = (float*)d_out;

  char* ws = (char*)d_ws;
  ushort* h = (ushort*)(ws + OFF_H);

  gemm_bias_kernel<<<(N_NODES + 255) / 256, 256, 0, stream>>>(x, W, b, h);

  if (ws_size >= (size_t)WS_NEEDED) {
    int* row_start = (int*)(ws + OFF_ROWSTART);
    int2* bucketed = (int2*)(ws + OFF_BUCKETED);
    int2* sorted = (int2*)(ws + OFF_SORTED);
    int* blkhist = (int*)(ws + OFF_BLKHIST);
    int* btot = (int*)(ws + OFF_BTOT);
    int* bucket_base = (int*)(ws + OFF_BBASE);

    partA_kernel<<<NBLKP, 256, 0, stream>>>(erows, blkhist);
    partB1_kernel<<<NBUCK, 512, 0, stream>>>(blkhist, btot);
    partB2_kernel<<<1, 512, 0, stream>>>(btot, bucket_base);
    partC_kernel<<<NBLKP, 256, 0, stream>>>(erows, ecols, evals, blkhist,
                                            bucket_base, bucketed);
    partD_kernel<<<NBUCK, 512, 0, stream>>>(bucketed, bucket_base, row_start,
                                            sorted);
    spmm_csr_kernel<<<(N_NODES + 7) / 8, 256, 0, stream>>>(row_start, sorted,
                                                           h, out);
  } else {
    hipMemsetAsync(d_out, 0, (size_t)out_size * sizeof(float), stream);
    edge_scatter_kernel<<<(N_EDGES + 7) / 8, 256, 0, stream>>>(erows, ecols,
                                                               evals, h, out);
    const int n4 = out_size / 4;
    relu_kernel<<<(n4 + 255) / 256, 256, 0, stream>>>(out, n4);
  }
}

// Round 12
// 124.604 us; speedup vs baseline: 1.7422x; 1.0783x over previous
//
#include <hip/hip_runtime.h>

#define N_NODES 100000
#define N_EDGES 1600000
#define FT 128

#define NBUCK 391   // row buckets: bucket = row >> 8 (256 rows each)
#define EPB 4096    // edges per partition block
#define NBLKP ((N_EDGES + EPB - 1) / EPB)  // 391 partition blocks
#define CAP 6144    // staged edges per bucket (avg 4092, sigma 64)

// ---- workspace layout (bytes) ----------------------------------------------
// h_bf        [0,           25,600,000)   N_NODES*FT*2 (bf16)
// bucketed    [25,600,000,  38,400,000)   N_EDGES int2 (packed row8|col, val)
// blkhist     [38,400,000,  39,011,524)   NBLKP*NBUCK ints (block-major)
// btot        [39,011,524,  39,013,088)   NBUCK ints
// bucket_base [39,013,088,  39,014,656)   NBUCK+1 ints
#define OFF_H 0
#define OFF_BUCKETED 25600000
#define OFF_BLKHIST 38400000
#define OFF_BTOT 39011524
#define OFF_BBASE 39013088
#define WS_NEEDED 39014656

typedef __attribute__((ext_vector_type(8))) short bf16x8;
typedef __attribute__((ext_vector_type(4))) float f32x4;

// bf16 helpers (RNE pack, shift-unpack).
static __device__ __forceinline__ ushort f2bf(float f) {
  const unsigned u = __float_as_uint(f);
  return (ushort)((u + 0x7FFF + ((u >> 16) & 1)) >> 16);
}
static __device__ __forceinline__ float bf2f(ushort s) {
  return __uint_as_float((unsigned)s << 16);
}

// ---------------------------------------------------------------------------
// Kernel 1: dense projection  h = x @ W + b  (bf16 output) via MFMA.
// Block = 256 threads (4 waves); wave = 64 rows x 128 cols.
// ---------------------------------------------------------------------------
__global__ __launch_bounds__(256) void gemm_bias_kernel(
    const float* __restrict__ x,
    const float* __restrict__ W,
    const float* __restrict__ b,
    ushort* __restrict__ h) {
  __shared__ __align__(16) ushort whi[16384];
  __shared__ __align__(16) ushort wlo[16384];

  const int tid = threadIdx.x;

  for (int idx = tid; idx < 16384; idx += 256) {
    const int k = idx >> 7;
    const int col = idx & 127;
    const float wv = W[idx];
    const ushort hi = f2bf(wv);
    const ushort lo = f2bf(wv - bf2f(hi));
    const int lane_ = (((k >> 3) & 3) << 4) | (col & 15);
    const int pos = ((((k >> 5) << 3) + (col >> 4)) * 64 + lane_) * 8 + (k & 7);
    whi[pos] = hi;
    wlo[pos] = lo;
  }
  __syncthreads();

  const int w = tid >> 6;
  const int lane = tid & 63;
  const int r0 = blockIdx.x * 256 + w * 64;
  const int arow = lane & 15;
  const int kgrp = (lane >> 4) << 3;

  float bias_v[8];
#pragma unroll
  for (int ct = 0; ct < 8; ++ct) bias_v[ct] = b[ct * 16 + (lane & 15)];

  f32x4 acc[4][8];
#pragma unroll
  for (int rf = 0; rf < 4; ++rf)
#pragma unroll
    for (int ct = 0; ct < 8; ++ct) acc[rf][ct] = (f32x4){0.f, 0.f, 0.f, 0.f};

#pragma unroll
  for (int ks = 0; ks < 4; ++ks) {
    bf16x8 afr[4];
#pragma unroll
    for (int rf = 0; rf < 4; ++rf) {
      int r = r0 + rf * 16 + arow;
      r = (r < N_NODES) ? r : (N_NODES - 1);
      const float* xp = x + (size_t)r * FT + ks * 32 + kgrp;
      const float4 u0 = *(const float4*)xp;
      const float4 u1 = *(const float4*)(xp + 4);
      bf16x8 a;
      a[0] = (short)f2bf(u0.x);
      a[1] = (short)f2bf(u0.y);
      a[2] = (short)f2bf(u0.z);
      a[3] = (short)f2bf(u0.w);
      a[4] = (short)f2bf(u1.x);
      a[5] = (short)f2bf(u1.y);
      a[6] = (short)f2bf(u1.z);
      a[7] = (short)f2bf(u1.w);
      afr[rf] = a;
    }
#pragma unroll
    for (int ct = 0; ct < 8; ++ct) {
      const int fo = ((ks * 8 + ct) * 64 + lane) * 8;
      const bf16x8 bh = *(const bf16x8*)&whi[fo];
      const bf16x8 bl = *(const bf16x8*)&wlo[fo];
#pragma unroll
      for (int rf = 0; rf < 4; ++rf) {
        acc[rf][ct] = __builtin_amdgcn_mfma_f32_16x16x32_bf16(
            afr[rf], bh, acc[rf][ct], 0, 0, 0);
        acc[rf][ct] = __builtin_amdgcn_mfma_f32_16x16x32_bf16(
            afr[rf], bl, acc[rf][ct], 0, 0, 0);
      }
    }
  }

  const int crow0 = (lane >> 4) << 2;
  const int ccol = lane & 15;
#pragma unroll
  for (int rf = 0; rf < 4; ++rf) {
#pragma unroll
    for (int ct = 0; ct < 8; ++ct) {
      const int col = ct * 16 + ccol;
#pragma unroll
      for (int i = 0; i < 4; ++i) {
        const int row = r0 + rf * 16 + crow0 + i;
        if (row < N_NODES)
          h[(size_t)row * FT + col] = f2bf(acc[rf][ct][i] + bias_v[ct]);
      }
    }
  }
}

// ---------------------------------------------------------------------------
// Pass A: per-block LDS histogram over row buckets -> blkhist[block][bucket].
// ---------------------------------------------------------------------------
__global__ __launch_bounds__(256) void partA_kernel(
    const int* __restrict__ erows, int* __restrict__ blkhist) {
  __shared__ int cnt[NBUCK];
  const int tid = threadIdx.x;
  for (int j = tid; j < NBUCK; j += 256) cnt[j] = 0;
  __syncthreads();

  const int base4 = blockIdx.x * (EPB / 4);
#pragma unroll
  for (int it = 0; it < EPB / 4 / 256; ++it) {
    const int idx4 = base4 + it * 256 + tid;
    if (idx4 < N_EDGES / 4) {
      const int4 r = ((const int4*)erows)[idx4];
      atomicAdd(&cnt[r.x >> 8], 1);
      atomicAdd(&cnt[r.y >> 8], 1);
      atomicAdd(&cnt[r.z >> 8], 1);
      atomicAdd(&cnt[r.w >> 8], 1);
    }
  }
  __syncthreads();
  int* dst = blkhist + (size_t)blockIdx.x * NBUCK;
  for (int j = tid; j < NBUCK; j += 256) dst[j] = cnt[j];
}

// ---------------------------------------------------------------------------
// Pass B1: for each bucket b, exclusive-scan blkhist[k][b] over k (in place);
// btot[b] = total.
// ---------------------------------------------------------------------------
__global__ __launch_bounds__(512) void partB1_kernel(
    int* __restrict__ blkhist, int* __restrict__ btot) {
  __shared__ int ps[512];
  const int b = blockIdx.x;
  const int t = threadIdx.x;
  int v = 0;
  if (t < NBLKP) v = blkhist[(size_t)t * NBUCK + b];
  ps[t] = v;
  __syncthreads();
#pragma unroll
  for (int d = 1; d < 512; d <<= 1) {
    const int u = (t >= d) ? ps[t - d] : 0;
    __syncthreads();
    ps[t] += u;
    __syncthreads();
  }
  if (t < NBLKP) blkhist[(size_t)t * NBUCK + b] = ps[t] - v;  // exclusive
  if (t == NBLKP - 1) btot[b] = ps[t];
}

// ---------------------------------------------------------------------------
// Pass B2: exclusive-scan btot -> bucket_base (+ sentinel = N_EDGES).
// ---------------------------------------------------------------------------
__global__ __launch_bounds__(512) void partB2_kernel(
    const int* __restrict__ btot, int* __restrict__ bucket_base) {
  __shared__ int ps[512];
  const int t = threadIdx.x;
  int v = 0;
  if (t < NBUCK) v = btot[t];
  ps[t] = v;
  __syncthreads();
#pragma unroll
  for (int d = 1; d < 512; d <<= 1) {
    const int u = (t >= d) ? ps[t - d] : 0;
    __syncthreads();
    ps[t] += u;
    __syncthreads();
  }
  if (t < NBUCK) bucket_base[t] = ps[t] - v;
  if (t == NBUCK - 1) bucket_base[NBUCK] = ps[t];
}

// ---------------------------------------------------------------------------
// Pass C: partition scatter. LDS cursors = absolute offsets; each edge goes
// to its bucket region packed as ((row&255)<<24 | col, val_bits).
// ---------------------------------------------------------------------------
__global__ __launch_bounds__(256) void partC_kernel(
    const int* __restrict__ erows,
    const int* __restrict__ ecols,
    const float* __restrict__ evals,
    const int* __restrict__ blkhist,
    const int* __restrict__ bucket_base,
    int2* __restrict__ bucketed) {
  __shared__ int cur[NBUCK];
  const int tid = threadIdx.x;
  const int* src = blkhist + (size_t)blockIdx.x * NBUCK;
  for (int j = tid; j < NBUCK; j += 256) cur[j] = src[j] + bucket_base[j];
  __syncthreads();

  const int base4 = blockIdx.x * (EPB / 4);
#pragma unroll
  for (int it = 0; it < EPB / 4 / 256; ++it) {
    const int idx4 = base4 + it * 256 + tid;
    if (idx4 < N_EDGES / 4) {
      const int4 r = ((const int4*)erows)[idx4];
      const int4 c = ((const int4*)ecols)[idx4];
      const float4 v = ((const float4*)evals)[idx4];
      int p;
      p = atomicAdd(&cur[r.x >> 8], 1);
      bucketed[p] = (int2){((r.x & 255) << 24) | c.x, __float_as_int(v.x)};
      p = atomicAdd(&cur[r.y >> 8], 1);
      bucketed[p] = (int2){((r.y & 255) << 24) | c.y, __float_as_int(v.y)};
      p = atomicAdd(&cur[r.z >> 8], 1);
      bucketed[p] = (int2){((r.z & 255) << 24) | c.z, __float_as_int(v.z)};
      p = atomicAdd(&cur[r.w >> 8], 1);
      bucketed[p] = (int2){((r.w & 255) << 24) | c.w, __float_as_int(v.w)};
    }
  }
}

// ---------------------------------------------------------------------------
// Fused D + SpMM: one block per bucket. Stage the bucket's edges in LDS,
// counting-sort them by row IN LDS, then per-row gather+FMA+ReLU and a
// single coalesced out write. No global sorted array, no row_start.
// Overflow (bucket > CAP, ~impossible for uniform rows) handled by a
// correct linear scan of the tail directly from global memory.
// ---------------------------------------------------------------------------
__global__ __launch_bounds__(512) void spmm_bucket_kernel(
    const int2* __restrict__ bucketed,
    const int* __restrict__ bucket_base,
    const ushort* __restrict__ h,
    float* __restrict__ out) {
  __shared__ int2 eds[CAP];   // 48 KB
  __shared__ int cnt[256];
  __shared__ int pos[256];
  __shared__ int cur[256];
  const int b = blockIdx.x;
  const int t = threadIdx.x;
  const int beg = bucket_base[b];
  const int end = bucket_base[b + 1];
  const int n = end - beg;
  const int m = (n < CAP) ? n : CAP;

  if (t < 256) cnt[t] = 0;
  __syncthreads();

  for (int i = t; i < m; i += 512)
    atomicAdd(&cnt[((unsigned)bucketed[beg + i].x) >> 24], 1);
  __syncthreads();

  if (t < 256) pos[t] = cnt[t];
  __syncthreads();
#pragma unroll
  for (int d = 1; d < 256; d <<= 1) {
    int u = 0;
    if (t < 256 && t >= d) u = pos[t - d];
    __syncthreads();
    if (t < 256) pos[t] += u;
    __syncthreads();
  }
  if (t < 256) {
    const int excl = pos[t] - cnt[t];
    pos[t] = excl;
    cur[t] = excl;
  }
  __syncthreads();

  for (int i = t; i < m; i += 512) {
    const int2 rec = bucketed[beg + i];
    const int r8 = ((unsigned)rec.x) >> 24;
    const int p = atomicAdd(&cur[r8], 1);
    eds[p] = (int2){rec.x & 0x00FFFFFF, rec.y};
  }
  __syncthreads();

  const int g = t >> 5;          // row group 0..15
  const int lane = t & 31;
  const int j = lane * 4;        // col base

  for (int rr = 0; rr < 16; ++rr) {
    const int r = rr * 16 + g;   // interleaved rows for load balance
    const int row = b * 256 + r;
    const int rbeg = pos[r];
    const int rend = cur[r];

    float a0 = 0.f, a1 = 0.f, a2 = 0.f, a3 = 0.f;
    int e = rbeg;
    for (; e + 3 < rend; e += 4) {
      const int2 p0 = eds[e];
      const int2 p1 = eds[e + 1];
      const int2 p2 = eds[e + 2];
      const int2 p3 = eds[e + 3];
      const ushort4 q0 = *(const ushort4*)(h + (size_t)p0.x * FT + j);
      const ushort4 q1 = *(const ushort4*)(h + (size_t)p1.x * FT + j);
      const ushort4 q2 = *(const ushort4*)(h + (size_t)p2.x * FT + j);
      const ushort4 q3 = *(const ushort4*)(h + (size_t)p3.x * FT + j);
      const float v0 = __int_as_float(p0.y);
      const float v1 = __int_as_float(p1.y);
      const float v2 = __int_as_float(p2.y);
      const float v3 = __int_as_float(p3.y);
      a0 = fmaf(v0, bf2f(q0.x), a0);
      a1 = fmaf(v0, bf2f(q0.y), a1);
      a2 = fmaf(v0, bf2f(q0.z), a2);
      a3 = fmaf(v0, bf2f(q0.w), a3);
      a0 = fmaf(v1, bf2f(q1.x), a0);
      a1 = fmaf(v1, bf2f(q1.y), a1);
      a2 = fmaf(v1, bf2f(q1.z), a2);
      a3 = fmaf(v1, bf2f(q1.w), a3);
      a0 = fmaf(v2, bf2f(q2.x), a0);
      a1 = fmaf(v2, bf2f(q2.y), a1);
      a2 = fmaf(v2, bf2f(q2.z), a2);
      a3 = fmaf(v2, bf2f(q2.w), a3);
      a0 = fmaf(v3, bf2f(q3.x), a0);
      a1 = fmaf(v3, bf2f(q3.y), a1);
      a2 = fmaf(v3, bf2f(q3.z), a2);
      a3 = fmaf(v3, bf2f(q3.w), a3);
    }
    for (; e < rend; ++e) {
      const int2 p0 = eds[e];
      const float v0 = __int_as_float(p0.y);
      const ushort4 q0 = *(const ushort4*)(h + (size_t)p0.x * FT + j);
      a0 = fmaf(v0, bf2f(q0.x), a0);
      a1 = fmaf(v0, bf2f(q0.y), a1);
      a2 = fmaf(v0, bf2f(q0.z), a2);
      a3 = fmaf(v0, bf2f(q0.w), a3);
    }
    if (n > CAP) {  // correctness fallback, statistically never taken
      for (int i = beg + CAP; i < end; ++i) {
        const int2 rec = bucketed[i];
        if ((int)(((unsigned)rec.x) >> 24) == r) {
          const float v0 = __int_as_float(rec.y);
          const ushort4 q0 =
              *(const ushort4*)(h + (size_t)(rec.x & 0x00FFFFFF) * FT + j);
          a0 = fmaf(v0, bf2f(q0.x), a0);
          a1 = fmaf(v0, bf2f(q0.y), a1);
          a2 = fmaf(v0, bf2f(q0.z), a2);
          a3 = fmaf(v0, bf2f(q0.w), a3);
        }
      }
    }

    if (row < N_NODES) {
      float4 o;
      o.x = fmaxf(a0, 0.f);
      o.y = fmaxf(a1, 0.f);
      o.z = fmaxf(a2, 0.f);
      o.w = fmaxf(a3, 0.f);
      *(float4*)(out + (size_t)row * FT + j) = o;
    }
  }
}

// ---------------------------------------------------------------------------
// Fallback (small ws): atomic scatter + relu on bf16 h.
// ---------------------------------------------------------------------------
__global__ __launch_bounds__(256) void edge_scatter_kernel(
    const int* __restrict__ erows,
    const int* __restrict__ ecols,
    const float* __restrict__ evals,
    const ushort* __restrict__ h,
    float* out) {
  const int tid = threadIdx.x;
  const int e = blockIdx.x * 8 + (tid >> 5);
  if (e >= N_EDGES) return;
  const int r = erows[e];
  const int c = ecols[e];
  const float v = evals[e];
  const int j = (tid & 31) * 4;
  const ushort4 q = *(const ushort4*)(h + (size_t)c * FT + j);
  float* op = out + (size_t)r * FT + j;
  atomicAdd(op + 0, v * bf2f(q.x));
  atomicAdd(op + 1, v * bf2f(q.y));
  atomicAdd(op + 2, v * bf2f(q.z));
  atomicAdd(op + 3, v * bf2f(q.w));
}

__global__ __launch_bounds__(256) void relu_kernel(float* out, int n4) {
  const int i = blockIdx.x * blockDim.x + threadIdx.x;
  if (i < n4) {
    float4 v = ((float4*)out)[i];
    v.x = fmaxf(v.x, 0.f);
    v.y = fmaxf(v.y, 0.f);
    v.z = fmaxf(v.z, 0.f);
    v.w = fmaxf(v.w, 0.f);
    ((float4*)out)[i] = v;
  }
}

extern "C" void kernel_launch(void* const* d_in, const int* in_sizes, int n_in,
                              void* d_out, int out_size, void* d_ws, size_t ws_size,
                              hipStream_t stream) {
  const float* x = (const float*)d_in[0];
  const int* erows = (const int*)d_in[1];
  const int* ecols = (const int*)d_in[2];
  const float* evals = (const float*)d_in[3];
  const float* W = (const float*)d_in[4];
  const float* b = (const float*)d_in[5];
  float* out = (float*)d_out;

  char* ws = (char*)d_ws;
  ushort* h = (ushort*)(ws + OFF_H);

  gemm_bias_kernel<<<(N_NODES + 255) / 256, 256, 0, stream>>>(x, W, b, h);

  if (ws_size >= (size_t)WS_NEEDED) {
    int2* bucketed = (int2*)(ws + OFF_BUCKETED);
    int* blkhist = (int*)(ws + OFF_BLKHIST);
    int* btot = (int*)(ws + OFF_BTOT);
    int* bucket_base = (int*)(ws + OFF_BBASE);

    partA_kernel<<<NBLKP, 256, 0, stream>>>(erows, blkhist);
    partB1_kernel<<<NBUCK, 512, 0, stream>>>(blkhist, btot);
    partB2_kernel<<<1, 512, 0, stream>>>(btot, bucket_base);
    partC_kernel<<<NBLKP, 256, 0, stream>>>(erows, ecols, evals, blkhist,
                                            bucket_base, bucketed);
    spmm_bucket_kernel<<<NBUCK, 512, 0, stream>>>(bucketed, bucket_base, h,
                                                  out);
  } else {
    hipMemsetAsync(d_out, 0, (size_t)out_size * sizeof(float), stream);
    edge_scatter_kernel<<<(N_EDGES + 7) / 8, 256, 0, stream>>>(erows, ecols,
                                                               evals, h, out);
    const int n4 = out_size / 4;
    relu_kernel<<<(n4 + 255) / 256, 256, 0, stream>>>(out, n4);
  }
}